// Round 2
// baseline (350.775 us; speedup 1.0000x reference)
//
#include <hip/hip_runtime.h>
#include <hip/hip_bf16.h>

#define Bb 128
#define LQ 32
#define LD 512
#define Hh 768
#define Cc 128

#define DBLOCKS ((Bb * LD) / 64)   // 1024 doc blocks (64 rows each)
#define QBLOCKS ((Bb * LQ) / 64)   // 64 query blocks

typedef short bf16x8 __attribute__((ext_vector_type(8)));
typedef short bf16x4 __attribute__((ext_vector_type(4)));
typedef float f32x4 __attribute__((ext_vector_type(4)));

__device__ __forceinline__ short f2bf(float f) {
  union { float f; unsigned u; } v;
  v.f = f;
  unsigned u = v.u + (0x7FFFu + ((v.u >> 16) & 1u));  // RNE
  return (short)(u >> 16);
}

// K0: W (H,C) fp32 -> Wt (C,H) bf16 (transposed so B-chunks are row-contiguous)
__global__ __launch_bounds__(256) void k_wt(const float* __restrict__ W,
                                            short* __restrict__ Wt) {
  int idx = blockIdx.x * 256 + threadIdx.x;  // grid covers H*C exactly
  int h = idx >> 7;   // / 128
  int c = idx & 127;
  Wt[c * Hh + h] = f2bf(W[idx]);
}

// Query projection: Y = qh @ W + b_comp, masked. 64 blocks, tile 64x128, BK=64.
// m97-style 2-barrier K-loop, single-buffered LDS.
__global__ __launch_bounds__(256, 4) void k_proj_q(
    const float* __restrict__ qh, const short* __restrict__ Wt,
    const float* __restrict__ bcomp, const int* __restrict__ qmask,
    float* __restrict__ qv) {
  constexpr int ASTR = 144;          // 64 bf16 = 128 B + 16 pad
  constexpr int BSTR = 160;          // 64 bf16 = 128 B + 32 pad
  constexpr int ASZ = 64 * ASTR;     // 9 KB
  constexpr int BSZ = 128 * BSTR;    // 20 KB
  __shared__ __align__(16) char sm[ASZ + BSZ];

  const int tid = threadIdx.x;
  const int w = tid >> 6;
  const int lane = tid & 63;
  const int quad = lane >> 4;
  const int lm = lane & 15;

  const long row0b = (long)blockIdx.x * 64;

  const float* gA = qh + (row0b + w * 16 + (lane >> 4)) * (long)Hh + (lane & 15) * 4;
  const short* gB = Wt + (w * 32 + (lane >> 3)) * Hh + (lane & 7) * 8;
  const int aoff = (w * 16 + (lane >> 4)) * ASTR + (lane & 15) * 8;
  const int boff = (w * 32 + (lane >> 3)) * BSTR + (lane & 7) * 16;

  char* bufA = sm;
  char* bufB = sm + ASZ;

  f32x4 acc[8];
#pragma unroll
  for (int j = 0; j < 8; ++j) acc[j] = (f32x4){0.f, 0.f, 0.f, 0.f};

  float4 ar[4];
  bf16x8 br[4];
#pragma unroll
  for (int i = 0; i < 4; ++i) ar[i] = *(const float4*)(gA + i * 4 * Hh);
#pragma unroll
  for (int i = 0; i < 4; ++i) br[i] = *(const bf16x8*)(gB + i * 8 * Hh);

  for (int kk = 0; kk < Hh / 64; ++kk) {
    __syncthreads();
#pragma unroll
    for (int i = 0; i < 4; ++i) {
      bf16x4 p;
      p[0] = f2bf(ar[i].x); p[1] = f2bf(ar[i].y);
      p[2] = f2bf(ar[i].z); p[3] = f2bf(ar[i].w);
      *(bf16x4*)(bufA + aoff + i * 4 * ASTR) = p;
    }
#pragma unroll
    for (int i = 0; i < 4; ++i)
      *(bf16x8*)(bufB + boff + i * 8 * BSTR) = br[i];
    __syncthreads();

    {
      const long go = (kk + 1 < Hh / 64) ? (long)(kk + 1) * 64 : 0;
#pragma unroll
      for (int i = 0; i < 4; ++i) ar[i] = *(const float4*)(gA + i * 4 * Hh + go);
#pragma unroll
      for (int i = 0; i < 4; ++i) br[i] = *(const bf16x8*)(gB + i * 8 * Hh + go);
    }

#pragma unroll
    for (int ks = 0; ks < 2; ++ks) {
      bf16x8 fa = *(const bf16x8*)(bufA + (w * 16 + lm) * ASTR + ks * 64 + quad * 16);
#pragma unroll
      for (int j = 0; j < 8; ++j) {
        bf16x8 fb = *(const bf16x8*)(bufB + (j * 16 + lm) * BSTR + ks * 64 + quad * 16);
        acc[j] = __builtin_amdgcn_mfma_f32_16x16x32_bf16(fa, fb, acc[j], 0, 0, 0);
      }
    }
  }

  const long row0 = row0b + w * 16;
  float bc[8];
#pragma unroll
  for (int j = 0; j < 8; ++j) bc[j] = bcomp[j * 16 + lm];

#pragma unroll
  for (int r = 0; r < 4; ++r) {
    const long row = row0 + quad * 4 + r;
    const float scale = (float)qmask[row];
    float* yr = qv + row * Cc;
#pragma unroll
    for (int j = 0; j < 8; ++j) yr[j * 16 + lm] = (acc[j][r] + bc[j]) * scale;
  }
}

// Fused doc projection + importance + scores + partial max.
// One block per (batch, 64-doc-token chunk). GEMM tile 64x128 as before, but
// d_vecs never leave registers: after the epilogue each lane holds
// vv[r][j] = d_vec[row=quad*4+r (+w*16)][col=j*16+lm]. Scores vs the batch's
// 32 q_vecs (staged in LDS at kernel start) are computed by per-lane partial
// dots + quad-wide butterfly sum (same reduction shape as the importance dot),
// then masked max -> pm[q][wave] -> partial[b][q][chunk].
// Eliminates the 32 MB dv write + 32 MB re-read and the whole k_scores kernel.
__global__ __launch_bounds__(256, 3) void k_doc_score(
    const float* __restrict__ dh, const short* __restrict__ Wt,
    const float* __restrict__ bcomp, const int* __restrict__ dmask,
    const float* __restrict__ wstop, const float* __restrict__ bstop,
    const float* __restrict__ qv, float* __restrict__ partial) {
  constexpr int ASTR = 144;
  constexpr int BSTR = 160;
  constexpr int ASZ = 64 * ASTR;     // 9 KB
  constexpr int BSZ = 128 * BSTR;    // 20 KB
  __shared__ __align__(16) char sm[ASZ + BSZ];  // 29 KB staging
  __shared__ float lq[LQ][Cc + 4];              // 16.9 KB q_vecs tile
  __shared__ float pm[LQ][4];                   // per-wave maxima

  const int tid = threadIdx.x;
  const int w = tid >> 6;
  const int lane = tid & 63;
  const int quad = lane >> 4;
  const int lm = lane & 15;

  const int b = blockIdx.x >> 3;     // batch
  const int chunk = blockIdx.x & 7;  // 64-token chunk within doc
  const long row0b = (long)b * LD + chunk * 64;

  // Stage this batch's q_vecs (32x128 fp32, 16 KB). Written before the
  // K-loop's first barrier; read only after the last one.
  {
    const float4* src = (const float4*)(qv + (size_t)b * LQ * Cc);
    for (int i = tid; i < LQ * Cc / 4; i += 256) {
      float4 v = src[i];
      int q = i >> 5;
      int c = (i & 31) << 2;
      *(float4*)&lq[q][c] = v;
    }
  }

  const float* gA = dh + (row0b + w * 16 + (lane >> 4)) * (long)Hh + (lane & 15) * 4;
  const short* gB = Wt + (w * 32 + (lane >> 3)) * Hh + (lane & 7) * 8;
  const int aoff = (w * 16 + (lane >> 4)) * ASTR + (lane & 15) * 8;
  const int boff = (w * 32 + (lane >> 3)) * BSTR + (lane & 7) * 16;

  char* bufA = sm;
  char* bufB = sm + ASZ;

  f32x4 acc[8];
#pragma unroll
  for (int j = 0; j < 8; ++j) acc[j] = (f32x4){0.f, 0.f, 0.f, 0.f};

  float4 ar[4];
  bf16x8 br[4];
#pragma unroll
  for (int i = 0; i < 4; ++i) ar[i] = *(const float4*)(gA + i * 4 * Hh);
#pragma unroll
  for (int i = 0; i < 4; ++i) br[i] = *(const bf16x8*)(gB + i * 8 * Hh);

  for (int kk = 0; kk < Hh / 64; ++kk) {
    __syncthreads();
#pragma unroll
    for (int i = 0; i < 4; ++i) {
      bf16x4 p;
      p[0] = f2bf(ar[i].x); p[1] = f2bf(ar[i].y);
      p[2] = f2bf(ar[i].z); p[3] = f2bf(ar[i].w);
      *(bf16x4*)(bufA + aoff + i * 4 * ASTR) = p;
    }
#pragma unroll
    for (int i = 0; i < 4; ++i)
      *(bf16x8*)(bufB + boff + i * 8 * BSTR) = br[i];
    __syncthreads();

    {
      const long go = (kk + 1 < Hh / 64) ? (long)(kk + 1) * 64 : 0;
#pragma unroll
      for (int i = 0; i < 4; ++i) ar[i] = *(const float4*)(gA + i * 4 * Hh + go);
#pragma unroll
      for (int i = 0; i < 4; ++i) br[i] = *(const bf16x8*)(gB + i * 8 * Hh + go);
    }

#pragma unroll
    for (int ks = 0; ks < 2; ++ks) {
      bf16x8 fa = *(const bf16x8*)(bufA + (w * 16 + lm) * ASTR + ks * 64 + quad * 16);
#pragma unroll
      for (int j = 0; j < 8; ++j) {
        bf16x8 fb = *(const bf16x8*)(bufB + (j * 16 + lm) * BSTR + ks * 64 + quad * 16);
        acc[j] = __builtin_amdgcn_mfma_f32_16x16x32_bf16(fa, fb, acc[j], 0, 0, 0);
      }
    }
  }

  // Epilogue: bias, importance (quad butterfly), mask -> vv in registers.
  const long row0 = row0b + w * 16;
  float bc[8], wsv[8];
#pragma unroll
  for (int j = 0; j < 8; ++j) bc[j] = bcomp[j * 16 + lm];
#pragma unroll
  for (int j = 0; j < 8; ++j) wsv[j] = wstop[j * 16 + lm];
  const float bs = bstop[0];

  float vv[4][8];
  int rm[4];
#pragma unroll
  for (int r = 0; r < 4; ++r) {
    const long row = row0 + quad * 4 + r;
    float v[8];
#pragma unroll
    for (int j = 0; j < 8; ++j) v[j] = acc[j][r] + bc[j];
    float p = 0.f;
#pragma unroll
    for (int j = 0; j < 8; ++j) p += v[j] * wsv[j];
    p += __shfl_xor(p, 1);
    p += __shfl_xor(p, 2);
    p += __shfl_xor(p, 4);
    p += __shfl_xor(p, 8);
    const float imp = fmaxf(p + bs, 0.f);
    const int m = dmask[row];
    rm[r] = m;
    const float scale = imp * (float)m;
#pragma unroll
    for (int j = 0; j < 8; ++j) vv[r][j] = v[j] * scale;
  }

  // Score phase: for each q row, per-lane partial dot over its 8 cols,
  // butterfly-sum across the quad's 16 lanes (completes the 128-dim dot),
  // masked max over this lane's 4 doc rows, then cross-quad max.
  // Explicit 8x4 tiling (all indices compile-time) keeps everything in regs.
#pragma unroll
  for (int qo = 0; qo < LQ; qo += 4) {
#pragma unroll
    for (int qi = 0; qi < 4; ++qi) {
      const int q = qo + qi;
      float ql[8];
#pragma unroll
      for (int j = 0; j < 8; ++j) ql[j] = lq[q][j * 16 + lm];
      float mx = -1000.f;
#pragma unroll
      for (int r = 0; r < 4; ++r) {
        float p = 0.f;
#pragma unroll
        for (int j = 0; j < 8; ++j) p += ql[j] * vv[r][j];
        p += __shfl_xor(p, 1);
        p += __shfl_xor(p, 2);
        p += __shfl_xor(p, 4);
        p += __shfl_xor(p, 8);
        const float s = rm[r] ? p : -1000.f;
        mx = fmaxf(mx, s);
      }
      mx = fmaxf(mx, __shfl_xor(mx, 16));
      mx = fmaxf(mx, __shfl_xor(mx, 32));
      if (lane == 0) pm[q][w] = mx;
    }
  }
  __syncthreads();
  if (tid < LQ) {
    float mx = fmaxf(fmaxf(pm[tid][0], pm[tid][1]), fmaxf(pm[tid][2], pm[tid][3]));
    partial[((size_t)b * LQ + tid) * 8 + chunk] = mx;
  }
}

// Finalize: cls dot on raw CLS vectors, max over chunks, masked sum, merge.
__global__ __launch_bounds__(256) void k_final(
    const float* __restrict__ qh, const float* __restrict__ dh,
    const int* __restrict__ qmask, const float* __restrict__ partial,
    const float* __restrict__ merger, float* __restrict__ out) {
  const int b = blockIdx.x;
  const int tid = threadIdx.x;
  __shared__ float red[256];
  __shared__ float clss;
  const float* qc = qh + (size_t)b * LQ * Hh;  // q row 0 = CLS
  const float* dc = dh + (size_t)b * LD * Hh;  // d row 0 = CLS
  float s = 0.f;
  for (int h = tid; h < Hh; h += 256) s += qc[h] * dc[h];
  red[tid] = s;
  __syncthreads();
  for (int off = 128; off > 0; off >>= 1) {
    if (tid < off) red[tid] += red[tid + off];
    __syncthreads();
  }
  if (tid == 0) clss = red[0];
  __syncthreads();
  float t = 0.f;
  if (tid < LQ) {
    const float* pp = partial + ((size_t)b * LQ + tid) * 8;
    float mx = pp[0];
#pragma unroll
    for (int c = 1; c < 8; ++c) mx = fmaxf(mx, pp[c]);
    if (qmask[b * LQ + tid]) t = mx;
  }
  red[tid] = t;
  __syncthreads();
  for (int off = 128; off > 0; off >>= 1) {
    if (tid < off) red[tid] += red[tid + off];
    __syncthreads();
  }
  if (tid == 0) {
    float w = 1.f / (1.f + expf(-merger[0]));
    float cs = clss * w;
    float ts = red[0] * (1.f - w);
    out[b] = cs + ts;        // score
    out[Bb + b] = cs;        // cls_score
    out[2 * Bb + b] = ts;    // term_score
  }
}

extern "C" void kernel_launch(void* const* d_in, const int* in_sizes, int n_in,
                              void* d_out, int out_size, void* d_ws, size_t ws_size,
                              hipStream_t stream) {
  const float* qh  = (const float*)d_in[0];  // (B,LQ,H)
  const float* dh  = (const float*)d_in[1];  // (B,LD,H)
  const int*   qm  = (const int*)d_in[2];    // (B,LQ)
  const int*   dm  = (const int*)d_in[3];    // (B,LD)
  const float* W   = (const float*)d_in[4];  // (H,C)
  const float* bc  = (const float*)d_in[5];  // (C)
  const float* wst = (const float*)d_in[6];  // (C,1)
  const float* bst = (const float*)d_in[7];  // (1)
  const float* mrg = (const float*)d_in[8];  // (1)
  float* out = (float*)d_out;                // 3*B floats

  char* ws = (char*)d_ws;
  short* Wt  = (short*)ws;                       // 192 KB bf16 W^T
  float* qv  = (float*)(ws + 196608);            // 2 MB q_vecs
  float* prt = (float*)(ws + 196608 + 2097152);  // 128 KB partial max

  k_wt<<<(Hh * Cc) / 256, 256, 0, stream>>>(W, Wt);
  k_proj_q<<<QBLOCKS, 256, 0, stream>>>(qh, Wt, bc, qm, qv);
  k_doc_score<<<DBLOCKS, 256, 0, stream>>>(dh, Wt, bc, dm, wst, bst, qv, prt);
  k_final<<<Bb, 256, 0, stream>>>(qh, dh, qm, prt, mrg, out);
}

// Round 3
// 331.303 us; speedup vs baseline: 1.0588x; 1.0588x over previous
//
#include <hip/hip_runtime.h>
#include <hip/hip_bf16.h>

#define Bb 128
#define LQ 32
#define LD 512
#define Hh 768
#define Cc 128

#define DBLOCKS ((Bb * LD) / 64)   // 1024 doc blocks (64 rows each)
#define QBLOCKS ((Bb * LQ) / 64)   // 64 query blocks

typedef short bf16x8 __attribute__((ext_vector_type(8)));
typedef short bf16x4 __attribute__((ext_vector_type(4)));
typedef float f32x4 __attribute__((ext_vector_type(4)));

__device__ __forceinline__ short f2bf(float f) {
  union { float f; unsigned u; } v;
  v.f = f;
  unsigned u = v.u + (0x7FFFu + ((v.u >> 16) & 1u));  // RNE
  return (short)(u >> 16);
}

// K0: W (H,C) fp32 -> Wt (C,H) bf16 (transposed so B-chunks are row-contiguous)
__global__ __launch_bounds__(256) void k_wt(const float* __restrict__ W,
                                            short* __restrict__ Wt) {
  int idx = blockIdx.x * 256 + threadIdx.x;  // grid covers H*C exactly
  int h = idx >> 7;   // / 128
  int c = idx & 127;
  Wt[c * Hh + h] = f2bf(W[idx]);
}

// Query projection: Y = qh @ W + b_comp, masked. 64 blocks, tile 64x128, BK=64.
// m97-style 2-barrier K-loop, single-buffered LDS.
__global__ __launch_bounds__(256, 4) void k_proj_q(
    const float* __restrict__ qh, const short* __restrict__ Wt,
    const float* __restrict__ bcomp, const int* __restrict__ qmask,
    float* __restrict__ qv) {
  constexpr int ASTR = 144;          // 64 bf16 = 128 B + 16 pad
  constexpr int BSTR = 160;          // 64 bf16 = 128 B + 32 pad
  constexpr int ASZ = 64 * ASTR;     // 9 KB
  constexpr int BSZ = 128 * BSTR;    // 20 KB
  __shared__ __align__(16) char sm[ASZ + BSZ];

  const int tid = threadIdx.x;
  const int w = tid >> 6;
  const int lane = tid & 63;
  const int quad = lane >> 4;
  const int lm = lane & 15;

  const long row0b = (long)blockIdx.x * 64;

  const float* gA = qh + (row0b + w * 16 + (lane >> 4)) * (long)Hh + (lane & 15) * 4;
  const short* gB = Wt + (w * 32 + (lane >> 3)) * Hh + (lane & 7) * 8;
  const int aoff = (w * 16 + (lane >> 4)) * ASTR + (lane & 15) * 8;
  const int boff = (w * 32 + (lane >> 3)) * BSTR + (lane & 7) * 16;

  char* bufA = sm;
  char* bufB = sm + ASZ;

  f32x4 acc[8];
#pragma unroll
  for (int j = 0; j < 8; ++j) acc[j] = (f32x4){0.f, 0.f, 0.f, 0.f};

  float4 ar[4];
  bf16x8 br[4];
#pragma unroll
  for (int i = 0; i < 4; ++i) ar[i] = *(const float4*)(gA + i * 4 * Hh);
#pragma unroll
  for (int i = 0; i < 4; ++i) br[i] = *(const bf16x8*)(gB + i * 8 * Hh);

  for (int kk = 0; kk < Hh / 64; ++kk) {
    __syncthreads();
#pragma unroll
    for (int i = 0; i < 4; ++i) {
      bf16x4 p;
      p[0] = f2bf(ar[i].x); p[1] = f2bf(ar[i].y);
      p[2] = f2bf(ar[i].z); p[3] = f2bf(ar[i].w);
      *(bf16x4*)(bufA + aoff + i * 4 * ASTR) = p;
    }
#pragma unroll
    for (int i = 0; i < 4; ++i)
      *(bf16x8*)(bufB + boff + i * 8 * BSTR) = br[i];
    __syncthreads();

    {
      const long go = (kk + 1 < Hh / 64) ? (long)(kk + 1) * 64 : 0;
#pragma unroll
      for (int i = 0; i < 4; ++i) ar[i] = *(const float4*)(gA + i * 4 * Hh + go);
#pragma unroll
      for (int i = 0; i < 4; ++i) br[i] = *(const bf16x8*)(gB + i * 8 * Hh + go);
    }

#pragma unroll
    for (int ks = 0; ks < 2; ++ks) {
      bf16x8 fa = *(const bf16x8*)(bufA + (w * 16 + lm) * ASTR + ks * 64 + quad * 16);
#pragma unroll
      for (int j = 0; j < 8; ++j) {
        bf16x8 fb = *(const bf16x8*)(bufB + (j * 16 + lm) * BSTR + ks * 64 + quad * 16);
        acc[j] = __builtin_amdgcn_mfma_f32_16x16x32_bf16(fa, fb, acc[j], 0, 0, 0);
      }
    }
  }

  const long row0 = row0b + w * 16;
  float bc[8];
#pragma unroll
  for (int j = 0; j < 8; ++j) bc[j] = bcomp[j * 16 + lm];

#pragma unroll
  for (int r = 0; r < 4; ++r) {
    const long row = row0 + quad * 4 + r;
    const float scale = (float)qmask[row];
    float* yr = qv + row * Cc;
#pragma unroll
    for (int j = 0; j < 8; ++j) yr[j * 16 + lm] = (acc[j][r] + bc[j]) * scale;
  }
}

// Fused doc projection + importance + scores + partial max.
// One block per (batch, 64-doc-token chunk). GEMM tile 64x128; d_vecs go
// through LDS (fp32, reusing the dead staging buffer) instead of HBM.
// Score phase = the proven k_scores formulation: per-thread (q,k) ownership,
// c-loop over float4 LDS reads, zero cross-lane shuffles (the round-2
// butterfly version was a ds_permute latency chain: 512 shuffles/lane).
// LDS layout (52992 B total, 3 blocks/CU):
//   [0,     33792) : GEMM staging (A 9216 + B 20480) -- then dv[64][132] fp32
//   [33792, 50688) : lq[32][132] fp32 (staged from qv at kernel start)
//   [50688, 50944) : dmsk[64]
//   [50944, 52992) : pm[32][16]
__global__ __launch_bounds__(256, 3) void k_doc_score(
    const float* __restrict__ dh, const short* __restrict__ Wt,
    const float* __restrict__ bcomp, const int* __restrict__ dmask,
    const float* __restrict__ wstop, const float* __restrict__ bstop,
    const float* __restrict__ qv, float* __restrict__ partial) {
  constexpr int ASTR = 144;
  constexpr int BSTR = 160;
  constexpr int ASZ = 64 * ASTR;     // 9216
  constexpr int BSZ = 128 * BSTR;    // 20480
  constexpr int DSTR = 132;          // fp32 row stride (+4 pad: 2-way max)
  constexpr int DVB = 64 * DSTR * 4; // 33792
  __shared__ __align__(16) char smem[DVB + 32 * DSTR * 4 + 256 + 2048];

  char* bufA = smem;
  char* bufB = smem + ASZ;
  float* dvt = (float*)smem;                       // [64][132], after GEMM
  float* lqt = (float*)(smem + DVB);               // [32][132]
  int* dmsk = (int*)(smem + DVB + 32 * DSTR * 4);  // [64]
  float* pm = (float*)(smem + DVB + 32 * DSTR * 4 + 256);  // [32][16]

  const int tid = threadIdx.x;
  const int w = tid >> 6;
  const int lane = tid & 63;
  const int quad = lane >> 4;
  const int lm = lane & 15;

  const int b = blockIdx.x >> 3;     // batch
  const int chunk = blockIdx.x & 7;  // 64-token chunk within doc
  const long row0b = (long)b * LD + chunk * 64;

  // Stage this batch's q_vecs (32x128 fp32) and the chunk's doc mask.
  // Both written before the K-loop's first barrier; read after the last one.
  {
    const float4* src = (const float4*)(qv + (size_t)b * LQ * Cc);
    for (int i = tid; i < LQ * Cc / 4; i += 256) {
      float4 v = src[i];
      int q = i >> 5;
      int c = (i & 31) << 2;
      *(float4*)&lqt[q * DSTR + c] = v;
    }
  }
  if (tid < 64) dmsk[tid] = dmask[row0b + tid];

  const float* gA = dh + (row0b + w * 16 + (lane >> 4)) * (long)Hh + (lane & 15) * 4;
  const short* gB = Wt + (w * 32 + (lane >> 3)) * Hh + (lane & 7) * 8;
  const int aoff = (w * 16 + (lane >> 4)) * ASTR + (lane & 15) * 8;
  const int boff = (w * 32 + (lane >> 3)) * BSTR + (lane & 7) * 16;

  f32x4 acc[8];
#pragma unroll
  for (int j = 0; j < 8; ++j) acc[j] = (f32x4){0.f, 0.f, 0.f, 0.f};

  float4 ar[4];
  bf16x8 br[4];
#pragma unroll
  for (int i = 0; i < 4; ++i) ar[i] = *(const float4*)(gA + i * 4 * Hh);
#pragma unroll
  for (int i = 0; i < 4; ++i) br[i] = *(const bf16x8*)(gB + i * 8 * Hh);

  for (int kk = 0; kk < Hh / 64; ++kk) {
    __syncthreads();
#pragma unroll
    for (int i = 0; i < 4; ++i) {
      bf16x4 p;
      p[0] = f2bf(ar[i].x); p[1] = f2bf(ar[i].y);
      p[2] = f2bf(ar[i].z); p[3] = f2bf(ar[i].w);
      *(bf16x4*)(bufA + aoff + i * 4 * ASTR) = p;
    }
#pragma unroll
    for (int i = 0; i < 4; ++i)
      *(bf16x8*)(bufB + boff + i * 8 * BSTR) = br[i];
    __syncthreads();

    {
      const long go = (kk + 1 < Hh / 64) ? (long)(kk + 1) * 64 : 0;
#pragma unroll
      for (int i = 0; i < 4; ++i) ar[i] = *(const float4*)(gA + i * 4 * Hh + go);
#pragma unroll
      for (int i = 0; i < 4; ++i) br[i] = *(const bf16x8*)(gB + i * 8 * Hh + go);
    }

#pragma unroll
    for (int ks = 0; ks < 2; ++ks) {
      bf16x8 fa = *(const bf16x8*)(bufA + (w * 16 + lm) * ASTR + ks * 64 + quad * 16);
#pragma unroll
      for (int j = 0; j < 8; ++j) {
        bf16x8 fb = *(const bf16x8*)(bufB + (j * 16 + lm) * BSTR + ks * 64 + quad * 16);
        acc[j] = __builtin_amdgcn_mfma_f32_16x16x32_bf16(fa, fb, acc[j], 0, 0, 0);
      }
    }
  }

  __syncthreads();  // all staging reads done -> safe to overwrite with dv

  // Epilogue: bias, importance (quad butterfly, 16 shuffles total), mask,
  // write the finished d_vec tile to LDS (fp32, stride 132: 2-way = free).
  float bc[8], wsv[8];
#pragma unroll
  for (int j = 0; j < 8; ++j) bc[j] = bcomp[j * 16 + lm];
#pragma unroll
  for (int j = 0; j < 8; ++j) wsv[j] = wstop[j * 16 + lm];
  const float bs = bstop[0];

#pragma unroll
  for (int r = 0; r < 4; ++r) {
    const int lrow = w * 16 + quad * 4 + r;  // chunk-local row
    float v[8];
#pragma unroll
    for (int j = 0; j < 8; ++j) v[j] = acc[j][r] + bc[j];
    float p = 0.f;
#pragma unroll
    for (int j = 0; j < 8; ++j) p += v[j] * wsv[j];
    p += __shfl_xor(p, 1);
    p += __shfl_xor(p, 2);
    p += __shfl_xor(p, 4);
    p += __shfl_xor(p, 8);
    const float imp = fmaxf(p + bs, 0.f);
    const float scale = imp * (float)dmsk[lrow];
#pragma unroll
    for (int j = 0; j < 8; ++j) dvt[lrow * DSTR + j * 16 + lm] = v[j] * scale;
  }
  __syncthreads();  // dv tile visible

  // Score phase (old k_scores inner loop): thread (qt,kt) owns q rows
  // {qt, qt+16} x doc rows kt*4..+3; accumulate over c in float4 steps.
  const int qt = tid & 15;
  const int kt = tid >> 4;
  const int kbase = kt * 4;
  float a[2][4];
#pragma unroll
  for (int qi = 0; qi < 2; ++qi)
#pragma unroll
    for (int ki = 0; ki < 4; ++ki) a[qi][ki] = 0.f;

  for (int c = 0; c < Cc; c += 4) {
    float4 q0 = *(float4*)&lqt[qt * DSTR + c];
    float4 q1 = *(float4*)&lqt[(qt + 16) * DSTR + c];
    float4 d0 = *(float4*)&dvt[(kbase + 0) * DSTR + c];
    float4 d1 = *(float4*)&dvt[(kbase + 1) * DSTR + c];
    float4 d2 = *(float4*)&dvt[(kbase + 2) * DSTR + c];
    float4 d3 = *(float4*)&dvt[(kbase + 3) * DSTR + c];
    a[0][0] += q0.x * d0.x + q0.y * d0.y + q0.z * d0.z + q0.w * d0.w;
    a[0][1] += q0.x * d1.x + q0.y * d1.y + q0.z * d1.z + q0.w * d1.w;
    a[0][2] += q0.x * d2.x + q0.y * d2.y + q0.z * d2.z + q0.w * d2.w;
    a[0][3] += q0.x * d3.x + q0.y * d3.y + q0.z * d3.z + q0.w * d3.w;
    a[1][0] += q1.x * d0.x + q1.y * d0.y + q1.z * d0.z + q1.w * d0.w;
    a[1][1] += q1.x * d1.x + q1.y * d1.y + q1.z * d1.z + q1.w * d1.w;
    a[1][2] += q1.x * d2.x + q1.y * d2.y + q1.z * d2.z + q1.w * d2.w;
    a[1][3] += q1.x * d3.x + q1.y * d3.y + q1.z * d3.z + q1.w * d3.w;
  }
  float m0 = -1000.f, m1 = -1000.f;
#pragma unroll
  for (int ki = 0; ki < 4; ++ki) {
    if (dmsk[kbase + ki]) {
      m0 = fmaxf(m0, a[0][ki]);
      m1 = fmaxf(m1, a[1][ki]);
    }
  }
  pm[qt * 16 + kt] = m0;
  pm[(qt + 16) * 16 + kt] = m1;
  __syncthreads();
  if (tid < LQ) {
    float mx = pm[tid * 16];
#pragma unroll
    for (int t = 1; t < 16; ++t) mx = fmaxf(mx, pm[tid * 16 + t]);
    partial[((size_t)b * LQ + tid) * 8 + chunk] = mx;
  }
}

// Finalize: cls dot on raw CLS vectors, max over chunks, masked sum, merge.
__global__ __launch_bounds__(256) void k_final(
    const float* __restrict__ qh, const float* __restrict__ dh,
    const int* __restrict__ qmask, const float* __restrict__ partial,
    const float* __restrict__ merger, float* __restrict__ out) {
  const int b = blockIdx.x;
  const int tid = threadIdx.x;
  __shared__ float red[256];
  __shared__ float clss;
  const float* qc = qh + (size_t)b * LQ * Hh;  // q row 0 = CLS
  const float* dc = dh + (size_t)b * LD * Hh;  // d row 0 = CLS
  float s = 0.f;
  for (int h = tid; h < Hh; h += 256) s += qc[h] * dc[h];
  red[tid] = s;
  __syncthreads();
  for (int off = 128; off > 0; off >>= 1) {
    if (tid < off) red[tid] += red[tid + off];
    __syncthreads();
  }
  if (tid == 0) clss = red[0];
  __syncthreads();
  float t = 0.f;
  if (tid < LQ) {
    const float* pp = partial + ((size_t)b * LQ + tid) * 8;
    float mx = pp[0];
#pragma unroll
    for (int c = 1; c < 8; ++c) mx = fmaxf(mx, pp[c]);
    if (qmask[b * LQ + tid]) t = mx;
  }
  red[tid] = t;
  __syncthreads();
  for (int off = 128; off > 0; off >>= 1) {
    if (tid < off) red[tid] += red[tid + off];
    __syncthreads();
  }
  if (tid == 0) {
    float w = 1.f / (1.f + expf(-merger[0]));
    float cs = clss * w;
    float ts = red[0] * (1.f - w);
    out[b] = cs + ts;        // score
    out[Bb + b] = cs;        // cls_score
    out[2 * Bb + b] = ts;    // term_score
  }
}

extern "C" void kernel_launch(void* const* d_in, const int* in_sizes, int n_in,
                              void* d_out, int out_size, void* d_ws, size_t ws_size,
                              hipStream_t stream) {
  const float* qh  = (const float*)d_in[0];  // (B,LQ,H)
  const float* dh  = (const float*)d_in[1];  // (B,LD,H)
  const int*   qm  = (const int*)d_in[2];    // (B,LQ)
  const int*   dm  = (const int*)d_in[3];    // (B,LD)
  const float* W   = (const float*)d_in[4];  // (H,C)
  const float* bc  = (const float*)d_in[5];  // (C)
  const float* wst = (const float*)d_in[6];  // (C,1)
  const float* bst = (const float*)d_in[7];  // (1)
  const float* mrg = (const float*)d_in[8];  // (1)
  float* out = (float*)d_out;                // 3*B floats

  char* ws = (char*)d_ws;
  short* Wt  = (short*)ws;                       // 192 KB bf16 W^T
  float* qv  = (float*)(ws + 196608);            // 2 MB q_vecs
  float* prt = (float*)(ws + 196608 + 2097152);  // 128 KB partial max

  k_wt<<<(Hh * Cc) / 256, 256, 0, stream>>>(W, Wt);
  k_proj_q<<<QBLOCKS, 256, 0, stream>>>(qh, Wt, bc, qm, qv);
  k_doc_score<<<DBLOCKS, 256, 0, stream>>>(dh, Wt, bc, dm, wst, bst, qv, prt);
  k_final<<<Bb, 256, 0, stream>>>(qh, dh, qm, prt, mrg, out);
}

// Round 4
// 319.467 us; speedup vs baseline: 1.0980x; 1.0370x over previous
//
#include <hip/hip_runtime.h>
#include <hip/hip_bf16.h>

#define Bb 128
#define LQ 32
#define LD 512
#define Hh 768
#define Cc 128

#define DBLOCKS ((Bb * LD) / 64)   // 1024 doc blocks (64 rows each)

typedef short bf16x8 __attribute__((ext_vector_type(8)));
typedef short bf16x4 __attribute__((ext_vector_type(4)));
typedef float f32x4 __attribute__((ext_vector_type(4)));

__device__ __forceinline__ short f2bf(float f) {
  union { float f; unsigned u; } v;
  v.f = f;
  unsigned u = v.u + (0x7FFFu + ((v.u >> 16) & 1u));  // RNE
  return (short)(u >> 16);
}

// K0: W (H,C) fp32 -> Wt (C,H) bf16 (transposed so B-chunks are row-contiguous)
__global__ __launch_bounds__(256) void k_wt(const float* __restrict__ W,
                                            short* __restrict__ Wt) {
  int idx = blockIdx.x * 256 + threadIdx.x;  // grid covers H*C exactly
  int h = idx >> 7;   // / 128
  int c = idx & 127;
  Wt[c * Hh + h] = f2bf(W[idx]);
}

// Fully fused: doc projection + query projection + importance + scores +
// partial max. One block per (batch, 64-doc-token chunk).
//
// Doc GEMM tile 64x128 via LDS staging (proven round-3 structure). Query
// projection (32 rows, identical B) rides along on waves 0-1: A_q fragments
// come direct global->reg->bf16 (built BEFORE the next-chunk prefetch
// overwrites the regs, so no double-buffer), and reuse each fb fragment for
// one extra MFMA. Bit-identical to the separate k_proj_q (same f2bf, same
// fragment order, same accumulate sequence). The q-epilogue writes lq LDS
// straight from accumulators -- no qv buffer, no k_proj_q launch, no
// serialization, no lq global staging.
//
// LDS layout (52992 B total, 3 blocks/CU):
//   [0,     33792) : GEMM staging (A 9216 + B 20480) -- then dv[64][132] fp32
//   [33792, 50688) : lq[32][132] fp32 (written by q-epilogue)
//   [50688, 50944) : dmsk[64]
//   [50944, 52992) : pm[32][16]
__global__ __launch_bounds__(256, 3) void k_fused(
    const float* __restrict__ dh, const float* __restrict__ qh,
    const short* __restrict__ Wt, const float* __restrict__ bcomp,
    const int* __restrict__ qmask, const int* __restrict__ dmask,
    const float* __restrict__ wstop, const float* __restrict__ bstop,
    float* __restrict__ partial) {
  constexpr int ASTR = 144;
  constexpr int BSTR = 160;
  constexpr int ASZ = 64 * ASTR;     // 9216
  constexpr int DSTR = 132;          // fp32 row stride (+4 pad: 2-way max)
  constexpr int DVB = 64 * DSTR * 4; // 33792 (>= ASZ + BSZ = 29696)
  __shared__ __align__(16) char smem[DVB + 32 * DSTR * 4 + 256 + 2048];

  char* bufA = smem;
  char* bufB = smem + ASZ;
  float* dvt = (float*)smem;                       // [64][132], after GEMM
  float* lqt = (float*)(smem + DVB);               // [32][132]
  int* dmsk = (int*)(smem + DVB + 32 * DSTR * 4);  // [64]
  float* pm = (float*)(smem + DVB + 32 * DSTR * 4 + 256);  // [32][16]

  const int tid = threadIdx.x;
  const int w = tid >> 6;
  const int lane = tid & 63;
  const int quad = lane >> 4;
  const int lm = lane & 15;
  const bool isq = (w < 2);  // waves 0-1 also compute q rows w*16..w*16+15

  const int b = blockIdx.x >> 3;     // batch
  const int chunk = blockIdx.x & 7;  // 64-token chunk within doc
  const long row0b = (long)b * LD + chunk * 64;

  if (tid < 64) dmsk[tid] = dmask[row0b + tid];

  const float* gA = dh + (row0b + w * 16 + (lane >> 4)) * (long)Hh + (lane & 15) * 4;
  const short* gB = Wt + (w * 32 + (lane >> 3)) * Hh + (lane & 7) * 8;
  const float* gQ = qh + ((long)b * LQ + w * 16 + lm) * Hh + quad * 8;
  const int aoff = (w * 16 + (lane >> 4)) * ASTR + (lane & 15) * 8;
  const int boff = (w * 32 + (lane >> 3)) * BSTR + (lane & 7) * 16;

  f32x4 acc[8], accq[8];
#pragma unroll
  for (int j = 0; j < 8; ++j) acc[j] = (f32x4){0.f, 0.f, 0.f, 0.f};
#pragma unroll
  for (int j = 0; j < 8; ++j) accq[j] = (f32x4){0.f, 0.f, 0.f, 0.f};

  float4 ar[4], aq[4];
  bf16x8 br[4];
  // preload chunk 0
#pragma unroll
  for (int i = 0; i < 4; ++i) ar[i] = *(const float4*)(gA + i * 4 * Hh);
#pragma unroll
  for (int i = 0; i < 4; ++i) br[i] = *(const bf16x8*)(gB + i * 8 * Hh);
  if (isq) {
#pragma unroll
    for (int i = 0; i < 4; ++i)
      aq[i] = *(const float4*)(gQ + (i >> 1) * 32 + (i & 1) * 4);
  }

  for (int kk = 0; kk < Hh / 64; ++kk) {
    __syncthreads();  // previous chunk's readers done
    // pack + write chunk kk regs -> LDS
#pragma unroll
    for (int i = 0; i < 4; ++i) {
      bf16x4 p;
      p[0] = f2bf(ar[i].x); p[1] = f2bf(ar[i].y);
      p[2] = f2bf(ar[i].z); p[3] = f2bf(ar[i].w);
      *(bf16x4*)(bufA + aoff + i * 4 * ASTR) = p;
    }
#pragma unroll
    for (int i = 0; i < 4; ++i)
      *(bf16x8*)(bufB + boff + i * 8 * BSTR) = br[i];
    __syncthreads();  // LDS tile visible

    // Build this chunk's q fragments from aq NOW (before prefetch clobbers).
    bf16x8 fq0, fq1;
    if (isq) {
      fq0[0] = f2bf(aq[0].x); fq0[1] = f2bf(aq[0].y);
      fq0[2] = f2bf(aq[0].z); fq0[3] = f2bf(aq[0].w);
      fq0[4] = f2bf(aq[1].x); fq0[5] = f2bf(aq[1].y);
      fq0[6] = f2bf(aq[1].z); fq0[7] = f2bf(aq[1].w);
      fq1[0] = f2bf(aq[2].x); fq1[1] = f2bf(aq[2].y);
      fq1[2] = f2bf(aq[2].z); fq1[3] = f2bf(aq[2].w);
      fq1[4] = f2bf(aq[3].x); fq1[5] = f2bf(aq[3].y);
      fq1[6] = f2bf(aq[3].z); fq1[7] = f2bf(aq[3].w);
    }

    // issue next-chunk global loads; they have the whole compute phase to land
    {
      const long go = (kk + 1 < Hh / 64) ? (long)(kk + 1) * 64 : 0;
#pragma unroll
      for (int i = 0; i < 4; ++i) ar[i] = *(const float4*)(gA + i * 4 * Hh + go);
#pragma unroll
      for (int i = 0; i < 4; ++i) br[i] = *(const bf16x8*)(gB + i * 8 * Hh + go);
      if (isq) {
#pragma unroll
        for (int i = 0; i < 4; ++i)
          aq[i] = *(const float4*)(gQ + go + (i >> 1) * 32 + (i & 1) * 4);
      }
    }

    // compute chunk kk: doc 16x128 per wave; waves 0-1 add q 16x128 reusing fb
#pragma unroll
    for (int ks = 0; ks < 2; ++ks) {
      bf16x8 fa = *(const bf16x8*)(bufA + (w * 16 + lm) * ASTR + ks * 64 + quad * 16);
      const bf16x8 fqk = (ks == 0) ? fq0 : fq1;
#pragma unroll
      for (int j = 0; j < 8; ++j) {
        bf16x8 fb = *(const bf16x8*)(bufB + (j * 16 + lm) * BSTR + ks * 64 + quad * 16);
        acc[j] = __builtin_amdgcn_mfma_f32_16x16x32_bf16(fa, fb, acc[j], 0, 0, 0);
        if (isq)
          accq[j] = __builtin_amdgcn_mfma_f32_16x16x32_bf16(fqk, fb, accq[j], 0, 0, 0);
      }
    }
  }

  __syncthreads();  // all staging reads done -> safe to overwrite with dv

  // Epilogue: bias, importance (quad butterfly), mask -> dvt LDS; waves 0-1
  // also write masked q_vecs -> lqt LDS straight from accumulators.
  float bc[8], wsv[8];
#pragma unroll
  for (int j = 0; j < 8; ++j) bc[j] = bcomp[j * 16 + lm];
#pragma unroll
  for (int j = 0; j < 8; ++j) wsv[j] = wstop[j * 16 + lm];
  const float bs = bstop[0];

#pragma unroll
  for (int r = 0; r < 4; ++r) {
    const int lrow = w * 16 + quad * 4 + r;  // chunk-local doc row
    float v[8];
#pragma unroll
    for (int j = 0; j < 8; ++j) v[j] = acc[j][r] + bc[j];
    float p = 0.f;
#pragma unroll
    for (int j = 0; j < 8; ++j) p += v[j] * wsv[j];
    p += __shfl_xor(p, 1);
    p += __shfl_xor(p, 2);
    p += __shfl_xor(p, 4);
    p += __shfl_xor(p, 8);
    const float imp = fmaxf(p + bs, 0.f);
    const float scale = imp * (float)dmsk[lrow];
#pragma unroll
    for (int j = 0; j < 8; ++j) dvt[lrow * DSTR + j * 16 + lm] = v[j] * scale;
  }
  if (isq) {
    const int qrow0 = w * 16 + quad * 4;
#pragma unroll
    for (int r = 0; r < 4; ++r) {
      const int qrow = qrow0 + r;
      const float scale = (float)qmask[b * LQ + qrow];
#pragma unroll
      for (int j = 0; j < 8; ++j)
        lqt[qrow * DSTR + j * 16 + lm] = (accq[j][r] + bc[j]) * scale;
    }
  }
  __syncthreads();  // dv + lq tiles visible

  // Score phase: thread (qt,kt) owns q rows {qt, qt+16} x doc rows kt*4..+3;
  // accumulate over c in float4 steps (zero cross-lane ops).
  const int qt = tid & 15;
  const int kt = tid >> 4;
  const int kbase = kt * 4;
  float a[2][4];
#pragma unroll
  for (int qi = 0; qi < 2; ++qi)
#pragma unroll
    for (int ki = 0; ki < 4; ++ki) a[qi][ki] = 0.f;

  for (int c = 0; c < Cc; c += 4) {
    float4 q0 = *(float4*)&lqt[qt * DSTR + c];
    float4 q1 = *(float4*)&lqt[(qt + 16) * DSTR + c];
    float4 d0 = *(float4*)&dvt[(kbase + 0) * DSTR + c];
    float4 d1 = *(float4*)&dvt[(kbase + 1) * DSTR + c];
    float4 d2 = *(float4*)&dvt[(kbase + 2) * DSTR + c];
    float4 d3 = *(float4*)&dvt[(kbase + 3) * DSTR + c];
    a[0][0] += q0.x * d0.x + q0.y * d0.y + q0.z * d0.z + q0.w * d0.w;
    a[0][1] += q0.x * d1.x + q0.y * d1.y + q0.z * d1.z + q0.w * d1.w;
    a[0][2] += q0.x * d2.x + q0.y * d2.y + q0.z * d2.z + q0.w * d2.w;
    a[0][3] += q0.x * d3.x + q0.y * d3.y + q0.z * d3.z + q0.w * d3.w;
    a[1][0] += q1.x * d0.x + q1.y * d0.y + q1.z * d0.z + q1.w * d0.w;
    a[1][1] += q1.x * d1.x + q1.y * d1.y + q1.z * d1.z + q1.w * d1.w;
    a[1][2] += q1.x * d2.x + q1.y * d2.y + q1.z * d2.z + q1.w * d2.w;
    a[1][3] += q1.x * d3.x + q1.y * d3.y + q1.z * d3.z + q1.w * d3.w;
  }
  float m0 = -1000.f, m1 = -1000.f;
#pragma unroll
  for (int ki = 0; ki < 4; ++ki) {
    if (dmsk[kbase + ki]) {
      m0 = fmaxf(m0, a[0][ki]);
      m1 = fmaxf(m1, a[1][ki]);
    }
  }
  pm[qt * 16 + kt] = m0;
  pm[(qt + 16) * 16 + kt] = m1;
  __syncthreads();
  if (tid < LQ) {
    float mx = pm[tid * 16];
#pragma unroll
    for (int t = 1; t < 16; ++t) mx = fmaxf(mx, pm[tid * 16 + t]);
    partial[((size_t)b * LQ + tid) * 8 + chunk] = mx;
  }
}

// Finalize: cls dot on raw CLS vectors, max over chunks, masked sum, merge.
__global__ __launch_bounds__(256) void k_final(
    const float* __restrict__ qh, const float* __restrict__ dh,
    const int* __restrict__ qmask, const float* __restrict__ partial,
    const float* __restrict__ merger, float* __restrict__ out) {
  const int b = blockIdx.x;
  const int tid = threadIdx.x;
  __shared__ float red[256];
  __shared__ float clss;
  const float* qc = qh + (size_t)b * LQ * Hh;  // q row 0 = CLS
  const float* dc = dh + (size_t)b * LD * Hh;  // d row 0 = CLS
  float s = 0.f;
  for (int h = tid; h < Hh; h += 256) s += qc[h] * dc[h];
  red[tid] = s;
  __syncthreads();
  for (int off = 128; off > 0; off >>= 1) {
    if (tid < off) red[tid] += red[tid + off];
    __syncthreads();
  }
  if (tid == 0) clss = red[0];
  __syncthreads();
  float t = 0.f;
  if (tid < LQ) {
    const float* pp = partial + ((size_t)b * LQ + tid) * 8;
    float mx = pp[0];
#pragma unroll
    for (int c = 1; c < 8; ++c) mx = fmaxf(mx, pp[c]);
    if (qmask[b * LQ + tid]) t = mx;
  }
  red[tid] = t;
  __syncthreads();
  for (int off = 128; off > 0; off >>= 1) {
    if (tid < off) red[tid] += red[tid + off];
    __syncthreads();
  }
  if (tid == 0) {
    float w = 1.f / (1.f + expf(-merger[0]));
    float cs = clss * w;
    float ts = red[0] * (1.f - w);
    out[b] = cs + ts;        // score
    out[Bb + b] = cs;        // cls_score
    out[2 * Bb + b] = ts;    // term_score
  }
}

extern "C" void kernel_launch(void* const* d_in, const int* in_sizes, int n_in,
                              void* d_out, int out_size, void* d_ws, size_t ws_size,
                              hipStream_t stream) {
  const float* qh  = (const float*)d_in[0];  // (B,LQ,H)
  const float* dh  = (const float*)d_in[1];  // (B,LD,H)
  const int*   qm  = (const int*)d_in[2];    // (B,LQ)
  const int*   dm  = (const int*)d_in[3];    // (B,LD)
  const float* W   = (const float*)d_in[4];  // (H,C)
  const float* bc  = (const float*)d_in[5];  // (C)
  const float* wst = (const float*)d_in[6];  // (C,1)
  const float* bst = (const float*)d_in[7];  // (1)
  const float* mrg = (const float*)d_in[8];  // (1)
  float* out = (float*)d_out;                // 3*B floats

  char* ws = (char*)d_ws;
  short* Wt  = (short*)ws;              // 192 KB bf16 W^T
  float* prt = (float*)(ws + 196608);   // 128 KB partial max

  k_wt<<<(Hh * Cc) / 256, 256, 0, stream>>>(W, Wt);
  k_fused<<<DBLOCKS, 256, 0, stream>>>(dh, qh, Wt, bc, qm, dm, wst, bst, prt);
  k_final<<<Bb, 256, 0, stream>>>(qh, dh, qm, prt, mrg, out);
}